// Round 12
// baseline (135.603 us; speedup 1.0000x reference)
//
#include <hip/hip_runtime.h>
#include <hip/hip_bf16.h>
#include <math.h>

#define NB 32
#define NS 1024
#define NH 512
#define NE 1024   // 2H
#define NEGV -1e10f

typedef _Float16 f16x8 __attribute__((ext_vector_type(8)));
typedef _Float16 f16x4 __attribute__((ext_vector_type(4)));
typedef float f32x4 __attribute__((ext_vector_type(4)));

__device__ __forceinline__ float fast_tanh(float x) {
  float t = __expf(2.f * x);
  return (t - 1.f) * __builtin_amdgcn_rcpf(t + 1.f);
}

// c[b][h] = b_attn[h] + sum_e hidden[b][e] * W_h[e][h]   (fp32, tiny)
__global__ __launch_bounds__(256) void proj_h_kernel(
    const float* __restrict__ hidden, const float* __restrict__ W_attn,
    const float* __restrict__ b_attn, float* __restrict__ c) {
  int b = blockIdx.x >> 1;
  int h = ((blockIdx.x & 1) << 8) + threadIdx.x;
  __shared__ float hid[NH];
  for (int e = threadIdx.x; e < NH; e += 256) hid[e] = hidden[b * NH + e];
  __syncthreads();
  float acc = b_attn[h];
#pragma unroll 8
  for (int e = 0; e < NH; ++e) acc = fmaf(hid[e], W_attn[(size_t)e * NH + h], acc);
  c[b * NH + h] = acc;
}

// WeT[col][k] = fp16(W_e[k][col]) — transposed so B k-runs are contiguous.
__global__ __launch_bounds__(256) void prep_We_kernel(
    const float* __restrict__ W_attn, _Float16* __restrict__ WeT) {
  int k = blockIdx.x;  // 0..1023
  const float* src = W_attn + (size_t)(NH + k) * NH;
#pragma unroll
  for (int j = 0; j < 2; ++j) {
    int col = threadIdx.x + (j << 8);
    WeT[(size_t)col * NE + k] = (_Float16)src[col];
  }
}

// Fused  tanh(enc@W_e + c) . W_v  partials over a 256-col chunk.
// BM=64, BN=256, BK=32, 256 thr / 4 waves (wave 64x64, acc 4x4).
// Depth-1 prefetch loop (R7/R10-proven): dbuf LDS, STAGE(t+1) issued BEFORE
// COMPUTE(t), single barrier drains after compute covered the latency.
// dbuf = 2 x 24 KB = 48 KB -> 3 resident blocks/CU (rotation overlap).
__global__ __launch_bounds__(256, 3) void score_kernel(
    const float* __restrict__ enc, const _Float16* __restrict__ WeT,
    const float* __restrict__ c, const float* __restrict__ Wv,
    float* __restrict__ spart) {
  __shared__ float Asm[2][64 * 32];       // fp32, 8 KB each, row stride 128 B
  __shared__ _Float16 Bsm[2][256 * 32];   // fp16, 16 KB each, col stride 64 B
  const int tid = threadIdx.x;
  const int lane = tid & 63;
  const int wc = tid >> 6;        // 0..3 = wave's 64-col slice
  const int r15 = lane & 15;
  const int id = blockIdx.x;                  // 0..511
  const int lb = ((id & 7) << 6) + (id >> 3); // bijective XCD swizzle (512%8==0)
  const int b = lb >> 4;
  const int s0 = (lb & 15) << 6;
  const int nc = blockIdx.y;                  // 0..1 column chunk of 256
  const char* Abase = (const char*)(enc + ((size_t)b * NS + s0) * NE);  // 4096 B rows
  const char* Wbase = (const char*)(WeT + ((size_t)(nc << 8)) * NE);    // 2048 B cols

  f32x4 acc[4][4];
#pragma unroll
  for (int i = 0; i < 4; ++i)
#pragma unroll
    for (int j = 0; j < 4; ++j) acc[i][j] = (f32x4)0.f;

  // A LDS: byte d <- linear src with in-row 16B-unit ^ (row&7)   [R3: 0 conflicts]
  // B LDS: byte d <- linear src with in-col 16B-unit ^ ((col>>1)&3) [2-way = free]
#define STAGE(KT, BUF)                                                           \
  {                                                                              \
    _Pragma("unroll") for (int p = 0; p < 2; ++p) {                              \
      int d = (p << 12) + (tid << 4);                                            \
      int row = d >> 7;                                                          \
      int sb = (d & 127) ^ ((row & 7) << 4);                                     \
      __builtin_amdgcn_global_load_lds(                                          \
          (const __attribute__((address_space(1))) uint32_t*)(Abase + (size_t)row * 4096 + ((KT) << 7) + sb), \
          (__attribute__((address_space(3))) uint32_t*)((char*)Asm[BUF] + (p << 12) + (wc << 10)), \
          16, 0, 0);                                                             \
    }                                                                            \
    _Pragma("unroll") for (int p = 0; p < 4; ++p) {                              \
      int d = (p << 12) + (tid << 4);                                            \
      int col = d >> 6;                                                          \
      int sb = (d & 63) ^ (((col >> 1) & 3) << 4);                               \
      __builtin_amdgcn_global_load_lds(                                          \
          (const __attribute__((address_space(1))) uint32_t*)(Wbase + (size_t)col * 2048 + ((KT) << 6) + sb), \
          (__attribute__((address_space(3))) uint32_t*)((char*)Bsm[BUF] + (p << 12) + (wc << 10)), \
          16, 0, 0);                                                             \
    }                                                                            \
  }

#define COMPUTE(CUR)                                                             \
  {                                                                              \
    f16x8 af[4], bf[4];                                                          \
    _Pragma("unroll") for (int mi = 0; mi < 4; ++mi) {                           \
      int row = (mi << 4) + r15;                                                 \
      int off1 = (row << 7) + ((lane >> 4) << 5);                                \
      int x = (row & 7) << 4;                                                    \
      f32x4 u = *(const f32x4*)((const char*)Asm[CUR] + (off1 ^ x));             \
      f32x4 v = *(const f32x4*)((const char*)Asm[CUR] + ((off1 + 16) ^ x));      \
      f16x8 h;                                                                   \
      h[0] = (_Float16)u[0]; h[1] = (_Float16)u[1];                              \
      h[2] = (_Float16)u[2]; h[3] = (_Float16)u[3];                              \
      h[4] = (_Float16)v[0]; h[5] = (_Float16)v[1];                              \
      h[6] = (_Float16)v[2]; h[7] = (_Float16)v[3];                              \
      af[mi] = h;                                                                \
    }                                                                            \
    _Pragma("unroll") for (int nj = 0; nj < 4; ++nj) {                           \
      int col = (wc << 6) + (nj << 4) + r15;                                     \
      int off = (col << 6) + ((lane >> 4) << 4);                                 \
      off ^= ((col >> 1) & 3) << 4;                                              \
      bf[nj] = *(const f16x8*)((const char*)Bsm[CUR] + off);                     \
    }                                                                            \
    _Pragma("unroll") for (int mi = 0; mi < 4; ++mi)                             \
      _Pragma("unroll") for (int nj = 0; nj < 4; ++nj)                           \
        acc[mi][nj] = __builtin_amdgcn_mfma_f32_16x16x32_f16(af[mi], bf[nj],     \
                                                             acc[mi][nj], 0, 0, 0); \
  }

  STAGE(0, 0);
  __syncthreads();
  for (int kt = 0; kt < 32; ++kt) {
    const int cur = kt & 1, nxt = cur ^ 1;
    if (kt < 31) STAGE(kt + 1, nxt);  // in flight during compute
    COMPUTE(cur);
    __syncthreads();                  // drains prefetch; reads done before overwrite
  }
#undef STAGE
#undef COMPUTE

  // ---- epilogue: fast-tanh + W_v dot over this wave's 64 cols ----
  float sr[4][4];
#pragma unroll
  for (int i = 0; i < 4; ++i)
#pragma unroll
    for (int r = 0; r < 4; ++r) sr[i][r] = 0.f;
#pragma unroll
  for (int nj = 0; nj < 4; ++nj) {
    int hcol = (nc << 8) + (wc << 6) + (nj << 4) + r15;
    float wvj = Wv[hcol];
    float cvj = c[b * NH + hcol];
#pragma unroll
    for (int mi = 0; mi < 4; ++mi)
#pragma unroll
      for (int r = 0; r < 4; ++r)
        sr[mi][r] += wvj * fast_tanh(acc[mi][nj][r] + cvj);
  }
  // reduce across the 16 col-lanes (fixed order -> deterministic)
#pragma unroll
  for (int off = 1; off < 16; off <<= 1)
#pragma unroll
    for (int mi = 0; mi < 4; ++mi)
#pragma unroll
      for (int r = 0; r < 4; ++r) sr[mi][r] += __shfl_xor(sr[mi][r], off, 64);
  if (r15 == 0) {
    float* dst = spart + (size_t)((nc << 2) + wc) * NB * NS + b * NS + s0;
#pragma unroll
    for (int mi = 0; mi < 4; ++mi)
#pragma unroll
      for (int r = 0; r < 4; ++r)
        dst[(mi << 4) + ((lane >> 4) << 2) + r] = sr[mi][r];
  }
}

// masked softmax over S per batch row; sums the 8 score partials first
__global__ __launch_bounds__(256) void softmax_kernel(
    const float* __restrict__ spart, const int* __restrict__ mask,
    float* __restrict__ attn) {
  int b = blockIdx.x, tid = threadIdx.x;
  __shared__ float red[8];
  float v[4];
  float mx = -INFINITY;
#pragma unroll
  for (int j = 0; j < 4; ++j) {
    int s = tid + (j << 8);
    float x = 0.f;
#pragma unroll
    for (int p = 0; p < 8; ++p) x += spart[(size_t)p * NB * NS + b * NS + s];
    v[j] = (mask[b * NS + s] == 0) ? NEGV : x;
    mx = fmaxf(mx, v[j]);
  }
#pragma unroll
  for (int off = 32; off >= 1; off >>= 1) mx = fmaxf(mx, __shfl_xor(mx, off, 64));
  if ((tid & 63) == 0) red[tid >> 6] = mx;
  __syncthreads();
  mx = fmaxf(fmaxf(red[0], red[1]), fmaxf(red[2], red[3]));
  float sum = 0.f;
#pragma unroll
  for (int j = 0; j < 4; ++j) {
    v[j] = __expf(v[j] - mx);
    sum += v[j];
  }
#pragma unroll
  for (int off = 32; off >= 1; off >>= 1) sum += __shfl_xor(sum, off, 64);
  __syncthreads();
  if ((tid & 63) == 0) red[4 + (tid >> 6)] = sum;
  __syncthreads();
  float inv = 1.f / (red[4] + red[5] + red[6] + red[7]);
#pragma unroll
  for (int j = 0; j < 4; ++j) attn[b * NS + tid + (j << 8)] = v[j] * inv;
}

// partial context over a 64-row S chunk (fp32 enc)
__global__ __launch_bounds__(256) void ctx_partial_kernel(
    const float* __restrict__ enc, const float* __restrict__ attn,
    float* __restrict__ partial) {
  int ch = blockIdx.x;  // 0..15
  int b = blockIdx.y;
  int tid = threadIdx.x;
  __shared__ float w[64];
  if (tid < 64) w[tid] = attn[b * NS + (ch << 6) + tid];
  __syncthreads();
  const float* encb = enc + ((size_t)b * NS + (ch << 6)) * NE;
  float4 acc = make_float4(0.f, 0.f, 0.f, 0.f);
  int e = tid << 2;
  for (int s = 0; s < 64; ++s) {
    float4 x = *(const float4*)(encb + (size_t)s * NE + e);
    float ws_ = w[s];
    acc.x = fmaf(ws_, x.x, acc.x);
    acc.y = fmaf(ws_, x.y, acc.y);
    acc.z = fmaf(ws_, x.z, acc.z);
    acc.w = fmaf(ws_, x.w, acc.w);
  }
  *(float4*)(partial + ((size_t)(b * 16 + ch)) * NE + e) = acc;
}

__global__ __launch_bounds__(256) void ctx_reduce_kernel(
    const float* __restrict__ partial, float* __restrict__ ctx) {
  int b = blockIdx.x;
  int e = threadIdx.x << 2;
  float4 acc = make_float4(0.f, 0.f, 0.f, 0.f);
  for (int ch = 0; ch < 16; ++ch) {
    float4 x = *(const float4*)(partial + ((size_t)(b * 16 + ch)) * NE + e);
    acc.x += x.x;
    acc.y += x.y;
    acc.z += x.z;
    acc.w += x.w;
  }
  *(float4*)(ctx + (size_t)b * NE + e) = acc;
}

extern "C" void kernel_launch(void* const* d_in, const int* in_sizes, int n_in,
                              void* d_out, int out_size, void* d_ws, size_t ws_size,
                              hipStream_t stream) {
  const float* hidden = (const float*)d_in[0];
  const float* enc = (const float*)d_in[1];
  const int* mask = (const int*)d_in[2];
  const float* W_attn = (const float*)d_in[3];
  const float* b_attn = (const float*)d_in[4];
  const float* W_v = (const float*)d_in[5];

  float* ctx = (float*)d_out;   // context: 32*1024
  float* attn = ctx + NB * NS;  // attn_w: 32*1024

  char* ws = (char*)d_ws;
  float* c = (float*)ws;                             // 64 KB
  float* spart = (float*)(ws + 65536);               // 8*32*1024 f32 = 1 MB
  float* partial = (float*)(ws + 65536 + 1048576);   // 32*16*1024 f32 = 2 MB
  _Float16* WeT = (_Float16*)(ws + 65536 + 1048576 + 2097152);  // 1 MB

  proj_h_kernel<<<64, 256, 0, stream>>>(hidden, W_attn, b_attn, c);
  prep_We_kernel<<<NE, 256, 0, stream>>>(W_attn, WeT);
  score_kernel<<<dim3(512, 2), 256, 0, stream>>>(enc, WeT, c, W_v, spart);
  softmax_kernel<<<NB, 256, 0, stream>>>(spart, mask, attn);
  ctx_partial_kernel<<<dim3(16, NB), 256, 0, stream>>>(enc, attn, partial);
  ctx_reduce_kernel<<<NB, 256, 0, stream>>>(partial, ctx);
}

// Round 14
// 103.075 us; speedup vs baseline: 1.3156x; 1.3156x over previous
//
#include <hip/hip_runtime.h>
#include <hip/hip_bf16.h>
#include <math.h>

#define NB 32
#define NS 1024
#define NH 512
#define NE 1024   // 2H
#define NEGV -1e10f

typedef _Float16 f16x8 __attribute__((ext_vector_type(8)));
typedef _Float16 f16x4 __attribute__((ext_vector_type(4)));
typedef float f32x4 __attribute__((ext_vector_type(4)));

__device__ __forceinline__ float fast_tanh(float x) {
  float t = __expf(2.f * x);
  return (t - 1.f) * __builtin_amdgcn_rcpf(t + 1.f);
}

// c[b][h] = b_attn[h] + sum_e hidden[b][e] * W_h[e][h]   (fp32, tiny)
__global__ __launch_bounds__(256) void proj_h_kernel(
    const float* __restrict__ hidden, const float* __restrict__ W_attn,
    const float* __restrict__ b_attn, float* __restrict__ c) {
  int b = blockIdx.x >> 1;
  int h = ((blockIdx.x & 1) << 8) + threadIdx.x;
  __shared__ float hid[NH];
  for (int e = threadIdx.x; e < NH; e += 256) hid[e] = hidden[b * NH + e];
  __syncthreads();
  float acc = b_attn[h];
#pragma unroll 8
  for (int e = 0; e < NH; ++e) acc = fmaf(hid[e], W_attn[(size_t)e * NH + h], acc);
  c[b * NH + h] = acc;
}

// Pack W_e into MFMA B-fragment order. BYTE layout:
//   (kt*8 + wid)*4096 + nj*1024 + lane*16  <-  halfs j=0..7 of
//   W_e[kt*32 + (lane>>4)*8 + j][wid*64 + nj*16 + (lane&15)]
__global__ __launch_bounds__(256) void prep_We_kernel(
    const float* __restrict__ W_attn, _Float16* __restrict__ Bp) {
  int kt = blockIdx.x;  // 0..31
  int t = threadIdx.x;
#pragma unroll
  for (int p = 0; p < 8; ++p) {
    int f = (p << 8) + t;        // 0..2047
    int wid = f >> 8;            // 0..7
    int nj = (f >> 6) & 3;       // 0..3
    int lane = f & 63;
    int col = (wid << 6) + (nj << 4) + (lane & 15);
    int kb = (kt << 5) + ((lane >> 4) << 3);
    f16x8 h;
#pragma unroll
    for (int j = 0; j < 8; ++j)
      h[j] = (_Float16)W_attn[(size_t)(NH + kb + j) * NH + col];
    *(f16x8*)((char*)Bp + (size_t)(((kt << 3) + wid) << 12) + (nj << 10) + (lane << 4)) = h;
  }
}

// Fused  tanh(enc@W_e + c) . W_v  partials.
// BM=64, BN=512 (A read ONCE), BK=32, 512 thr / 8 waves (wave 64x64, acc 4x4).
// A: raw fp32 via global_load_lds, dbuf 2x8 KB, issue-early, 1 barrier/K-step.
// B: NO LDS — fragment-packed fp16 from L2, contiguous 4 KB/wave/step,
//    depth-1 register prefetch with compile-time buffer indices (rule #20).
__global__ __launch_bounds__(512, 4) void score_kernel(
    const float* __restrict__ enc, const _Float16* __restrict__ Bp,
    const float* __restrict__ c, const float* __restrict__ Wv,
    float* __restrict__ spart) {
  __shared__ float Asm[2][64 * 32];  // fp32, 8 KB each, row stride 128 B
  const int tid = threadIdx.x;
  const int lane = tid & 63;
  const int wid = tid >> 6;        // 0..7 = wave's 64-col slice
  const int r15 = lane & 15;
  const int id = blockIdx.x;                  // 0..511
  const int mt = ((id & 7) << 6) + (id >> 3); // bijective XCD swizzle (512%8==0)
  const int b = mt >> 4;
  const int s0 = (mt & 15) << 6;
  const char* Abase = (const char*)(enc + ((size_t)b * NS + s0) * NE);  // 4096 B rows
  const char* Bbase = (const char*)Bp + ((size_t)wid << 12);  // this wave's stream

  f32x4 acc[4][4];
#pragma unroll
  for (int i = 0; i < 4; ++i)
#pragma unroll
    for (int j = 0; j < 4; ++j) acc[i][j] = (f32x4)0.f;

  // A LDS: byte d holds linear src (row = d>>7, in-row 16B-unit ^ (row&7))
  // [R7-proven geometry, 0 conflicts]. 1 gload_lds per thread per step.
#define STAGE_A(KT, BUF)                                                         \
  {                                                                              \
    int d = tid << 4;                                                            \
    int row = d >> 7;                                                            \
    int sb = (d & 127) ^ ((row & 7) << 4);                                       \
    __builtin_amdgcn_global_load_lds(                                            \
        (const __attribute__((address_space(1))) uint32_t*)(Abase + (size_t)row * 4096 + ((KT) << 7) + sb), \
        (__attribute__((address_space(3))) uint32_t*)((char*)Asm[BUF] + (wid << 10)), \
        16, 0, 0);                                                               \
  }

  // B fragments for step KT: 4 contiguous dwordx4 per lane (4 KB per wave).
  // byte offset = KT*32768 + nj*1024 + lane*16  (wid folded into Bbase)
#define BLOAD(S, KT)                                                             \
  _Pragma("unroll") for (int nj = 0; nj < 4; ++nj)                               \
      bf##S[nj] = *(const f16x8*)(Bbase + ((size_t)(KT) << 15) +                 \
                                  (nj << 10) + (lane << 4));

#define COMPUTE(CUR, S)                                                          \
  {                                                                              \
    f16x8 af[4];                                                                 \
    _Pragma("unroll") for (int mi = 0; mi < 4; ++mi) {                           \
      int row = (mi << 4) + r15;                                                 \
      int off1 = (row << 7) + ((lane >> 4) << 5);                                \
      int x = (row & 7) << 4;                                                    \
      f32x4 u = *(const f32x4*)((const char*)Asm[CUR] + (off1 ^ x));             \
      f32x4 v = *(const f32x4*)((const char*)Asm[CUR] + ((off1 + 16) ^ x));      \
      f16x8 h;                                                                   \
      h[0] = (_Float16)u[0]; h[1] = (_Float16)u[1];                              \
      h[2] = (_Float16)u[2]; h[3] = (_Float16)u[3];                              \
      h[4] = (_Float16)v[0]; h[5] = (_Float16)v[1];                              \
      h[6] = (_Float16)v[2]; h[7] = (_Float16)v[3];                              \
      af[mi] = h;                                                                \
    }                                                                            \
    _Pragma("unroll") for (int mi = 0; mi < 4; ++mi)                             \
      _Pragma("unroll") for (int nj = 0; nj < 4; ++nj)                           \
        acc[mi][nj] = __builtin_amdgcn_mfma_f32_16x16x32_f16(af[mi], bf##S[nj],  \
                                                             acc[mi][nj], 0, 0, 0); \
  }

  f16x8 bf0[4], bf1[4];
  STAGE_A(0, 0);
  BLOAD(0, 0);
  __syncthreads();
  // Unrolled in pairs so all buffer indices are compile-time (rule #20).
  for (int kt = 0; kt < 32; kt += 2) {
    STAGE_A(kt + 1, 1);
    BLOAD(1, kt + 1);
    COMPUTE(0, 0);
    __syncthreads();
    if (kt < 30) {
      STAGE_A(kt + 2, 0);
      BLOAD(0, kt + 2);
    }
    COMPUTE(1, 1);
    __syncthreads();
  }
#undef STAGE_A
#undef BLOAD
#undef COMPUTE

  // ---- epilogue: fast-tanh + W_v dot over this wave's 64 cols ----
  float sr[4][4];
#pragma unroll
  for (int i = 0; i < 4; ++i)
#pragma unroll
    for (int r = 0; r < 4; ++r) sr[i][r] = 0.f;
#pragma unroll
  for (int nj = 0; nj < 4; ++nj) {
    int hcol = (wid << 6) + (nj << 4) + r15;
    float wvj = Wv[hcol];
    float cvj = c[b * NH + hcol];
#pragma unroll
    for (int mi = 0; mi < 4; ++mi)
#pragma unroll
      for (int r = 0; r < 4; ++r)
        sr[mi][r] += wvj * fast_tanh(acc[mi][nj][r] + cvj);
  }
  // reduce across the 16 col-lanes (fixed order -> deterministic)
#pragma unroll
  for (int off = 1; off < 16; off <<= 1)
#pragma unroll
    for (int mi = 0; mi < 4; ++mi)
#pragma unroll
      for (int r = 0; r < 4; ++r) sr[mi][r] += __shfl_xor(sr[mi][r], off, 64);
  if (r15 == 0) {
    float* dst = spart + (size_t)wid * NB * NS + b * NS + s0;
#pragma unroll
    for (int mi = 0; mi < 4; ++mi)
#pragma unroll
      for (int r = 0; r < 4; ++r)
        dst[(mi << 4) + ((lane >> 4) << 2) + r] = sr[mi][r];
  }
}

// masked softmax over S per batch row; sums the 8 score partials first
__global__ __launch_bounds__(256) void softmax_kernel(
    const float* __restrict__ spart, const int* __restrict__ mask,
    float* __restrict__ attn) {
  int b = blockIdx.x, tid = threadIdx.x;
  __shared__ float red[8];
  float v[4];
  float mx = -INFINITY;
#pragma unroll
  for (int j = 0; j < 4; ++j) {
    int s = tid + (j << 8);
    float x = 0.f;
#pragma unroll
    for (int p = 0; p < 8; ++p) x += spart[(size_t)p * NB * NS + b * NS + s];
    v[j] = (mask[b * NS + s] == 0) ? NEGV : x;
    mx = fmaxf(mx, v[j]);
  }
#pragma unroll
  for (int off = 32; off >= 1; off >>= 1) mx = fmaxf(mx, __shfl_xor(mx, off, 64));
  if ((tid & 63) == 0) red[tid >> 6] = mx;
  __syncthreads();
  mx = fmaxf(fmaxf(red[0], red[1]), fmaxf(red[2], red[3]));
  float sum = 0.f;
#pragma unroll
  for (int j = 0; j < 4; ++j) {
    v[j] = __expf(v[j] - mx);
    sum += v[j];
  }
#pragma unroll
  for (int off = 32; off >= 1; off >>= 1) sum += __shfl_xor(sum, off, 64);
  __syncthreads();
  if ((tid & 63) == 0) red[4 + (tid >> 6)] = sum;
  __syncthreads();
  float inv = 1.f / (red[4] + red[5] + red[6] + red[7]);
#pragma unroll
  for (int j = 0; j < 4; ++j) attn[b * NS + tid + (j << 8)] = v[j] * inv;
}

// partial context over a 64-row S chunk (fp32 enc)
__global__ __launch_bounds__(256) void ctx_partial_kernel(
    const float* __restrict__ enc, const float* __restrict__ attn,
    float* __restrict__ partial) {
  int ch = blockIdx.x;  // 0..15
  int b = blockIdx.y;
  int tid = threadIdx.x;
  __shared__ float w[64];
  if (tid < 64) w[tid] = attn[b * NS + (ch << 6) + tid];
  __syncthreads();
  const float* encb = enc + ((size_t)b * NS + (ch << 6)) * NE;
  float4 acc = make_float4(0.f, 0.f, 0.f, 0.f);
  int e = tid << 2;
  for (int s = 0; s < 64; ++s) {
    float4 x = *(const float4*)(encb + (size_t)s * NE + e);
    float ws_ = w[s];
    acc.x = fmaf(ws_, x.x, acc.x);
    acc.y = fmaf(ws_, x.y, acc.y);
    acc.z = fmaf(ws_, x.z, acc.z);
    acc.w = fmaf(ws_, x.w, acc.w);
  }
  *(float4*)(partial + ((size_t)(b * 16 + ch)) * NE + e) = acc;
}

__global__ __launch_bounds__(256) void ctx_reduce_kernel(
    const float* __restrict__ partial, float* __restrict__ ctx) {
  int b = blockIdx.x;
  int e = threadIdx.x << 2;
  float4 acc = make_float4(0.f, 0.f, 0.f, 0.f);
  for (int ch = 0; ch < 16; ++ch) {
    float4 x = *(const float4*)(partial + ((size_t)(b * 16 + ch)) * NE + e);
    acc.x += x.x;
    acc.y += x.y;
    acc.z += x.z;
    acc.w += x.w;
  }
  *(float4*)(ctx + (size_t)b * NE + e) = acc;
}

extern "C" void kernel_launch(void* const* d_in, const int* in_sizes, int n_in,
                              void* d_out, int out_size, void* d_ws, size_t ws_size,
                              hipStream_t stream) {
  const float* hidden = (const float*)d_in[0];
  const float* enc = (const float*)d_in[1];
  const int* mask = (const int*)d_in[2];
  const float* W_attn = (const float*)d_in[3];
  const float* b_attn = (const float*)d_in[4];
  const float* W_v = (const float*)d_in[5];

  float* ctx = (float*)d_out;   // context: 32*1024
  float* attn = ctx + NB * NS;  // attn_w: 32*1024

  char* ws = (char*)d_ws;
  float* c = (float*)ws;                             // 64 KB
  float* spart = (float*)(ws + 65536);               // 8*32*1024 f32 = 1 MB
  float* partial = (float*)(ws + 65536 + 1048576);   // 32*16*1024 f32 = 2 MB
  _Float16* Bp = (_Float16*)(ws + 65536 + 1048576 + 2097152);  // 1 MB packed

  proj_h_kernel<<<64, 256, 0, stream>>>(hidden, W_attn, b_attn, c);
  prep_We_kernel<<<32, 256, 0, stream>>>(W_attn, Bp);
  score_kernel<<<512, 512, 0, stream>>>(enc, Bp, c, W_v, spart);
  softmax_kernel<<<NB, 256, 0, stream>>>(spart, mask, attn);
  ctx_partial_kernel<<<dim3(16, NB), 256, 0, stream>>>(enc, attn, partial);
  ctx_reduce_kernel<<<NB, 256, 0, stream>>>(partial, ctx);
}